// Round 7
// baseline (254.613 us; speedup 1.0000x reference)
//
#include <hip/hip_runtime.h>
#include <hip/hip_bf16.h>

// B=8, T=4096, C=32, D=64. Causal, no 1/sqrt(D) scaling.
constexpr int Bc = 8;
constexpr int Tt = 4096;
constexpr int Dd = 64;
constexpr int NT = 2080;          // k-tile units per batch = sum(qt+1), qt=0..63
constexpr int CPB = 8;            // k-tile units per block (2080 = 260*8 exact)
constexpr int BPB = NT / CPB;     // 260 blocks per batch

typedef __attribute__((ext_vector_type(8))) short short8;   // 8 bf16 = 4 VGPRs
typedef __attribute__((ext_vector_type(4))) float floatx4;  // MFMA C/D frag
typedef uint4   __attribute__((may_alias)) uint4_a;
typedef short8  __attribute__((may_alias)) short8_a;
typedef ushort4 __attribute__((may_alias)) ushort4_a;
typedef float4  __attribute__((may_alias)) float4_a;

#define MFMA16(A, B, C) __builtin_amdgcn_mfma_f32_16x16x32_bf16(A, B, C, 0, 0, 0)
constexpr float LOG2E = 1.4426950408889634f;

// ---- fast fp32 -> bf16: round-half-up (u + 0x8000), pack 2 via v_perm ----
__device__ __forceinline__ unsigned rnd16(float x) {
    unsigned u; __builtin_memcpy(&u, &x, 4); return u + 0x8000u;
}
__device__ __forceinline__ unsigned pk_bf2(float lo, float hi) {
    return __builtin_amdgcn_perm(rnd16(hi), rnd16(lo), 0x07060302);
}
__device__ __forceinline__ ushort4 pack4(floatx4 d) {
    union { unsigned u[2]; ushort4 v; } r;
    r.u[0] = pk_bf2(d[0], d[1]);
    r.u[1] = pk_bf2(d[2], d[3]);
    return r.v;
}
__device__ __forceinline__ short8 cvt8(float4 a, float4 b) {
    union { unsigned u[4]; short8 s; } r;
    r.u[0] = pk_bf2(a.x, a.y);
    r.u[1] = pk_bf2(a.z, a.w);
    r.u[2] = pk_bf2(b.x, b.y);
    r.u[3] = pk_bf2(b.z, b.w);
    return r.s;
}

// ---------------------------------------------------------------------------
__global__ __launch_bounds__(512) void zero_kernel(float4* __restrict__ p) {
    p[(size_t)blockIdx.x * 512 + threadIdx.x] = make_float4(0.f, 0.f, 0.f, 0.f);
}

// ---------------------------------------------------------------------------
// Uniform-work accumulator. Block = 256 threads (4 waves), processes EXACTLY
// 8 (qt,kt) tile-units from the batch's flat list (qt descending 63->0, kt
// ascending within qt). Partial (O, l) atomicAdd'ed into fp32 accumulators
// (valid because no-max softmax partials combine additively).
// Per tile: waves regenerate K/V^T into swizzled LDS via MFMA from x and
// register-resident W-frags; S^T via MFMA; exp2 (log2e in Wq); P^T per-wave
// LDS round-trip; O^T += V^T.P^T via MFMA. Q regen per-wave at qt changes.
// ---------------------------------------------------------------------------
__global__ __launch_bounds__(256, 5) void attn_accum(
    const float* __restrict__ x,
    const float* __restrict__ Wk, const float* __restrict__ Wq,
    const float* __restrict__ Wv,
    float* __restrict__ Oacc, float* __restrict__ Lacc)
{
    __shared__ uint4 sK[512];    // K tile [key 64][granule 8], XOR-swizzled (8 KB)
    __shared__ uint4 sVt[512];   // V^T tile [d 64][granule 8], XOR-swizzled (8 KB)
    __shared__ uint4 sP[512];    // per-wave P^T (2 KB each); doubles as sQ slot

    int b = blockIdx.x / BPB;
    int j = blockIdx.x % BPB;
    int f0 = j * CPB;

    // ---- solve start (qt, kt): largest n with n(n+1)/2 <= A-1, A = NT-f0 ----
    int A = NT - f0;
    int n = (int)((__builtin_sqrtf(8.f * (float)(A - 1) + 1.f) - 1.f) * 0.5f);
    while (n * (n + 1) / 2 > A - 1) --n;
    while ((n + 1) * (n + 2) / 2 <= A - 1) ++n;
    int qt_c = n;
    int kt_c = f0 - NT + (n + 1) * (n + 2) / 2;

    int tid  = threadIdx.x;
    int wave = tid >> 6, lane = tid & 63;
    int gw = wave;                     // 4 waves: wave gw owns q/keys 16gw..+15
    int ln15 = lane & 15, quad = lane >> 4;
    size_t bT = (size_t)b * Tt;

    // ---- loop-invariant Wk/Wv fragments (lane -> (d=16c+ln15, k=quad*8+j)) ----
    short8 wk_f[4], wv_f[4];
    #pragma unroll
    for (int c = 0; c < 4; ++c) {
        int col = 16*c + ln15;
        union { unsigned u[4]; short8 s; } rk, rv;
        #pragma unroll
        for (int jj = 0; jj < 4; ++jj) {
            const float* k0 = Wk + (quad*8 + 2*jj) * 64 + col;
            const float* v0 = Wv + (quad*8 + 2*jj) * 64 + col;
            rk.u[jj] = pk_bf2(k0[0], k0[64]);
            rv.u[jj] = pk_bf2(v0[0], v0[64]);
        }
        wk_f[c] = rk.s; wv_f[c] = rv.s;
    }

    short8 bq0, bq1;                   // Q B-frags (n=q=ln15, k=quad*8+j)
    floatx4 o4[4];
    float l_lane;

    // ---- per-wave Q regen for q-tile qt (no barrier: own sP slot only) ----
    unsigned short* sQh = (unsigned short*)sP + wave * 1024;
    auto regenQ = [&](int qtn) {
        const float* xp = x + (bT + qtn*64 + gw*16 + ln15) * 32 + quad*8;
        float4 x0 = ((const float4_a*)xp)[0];
        float4 x1 = ((const float4_a*)xp)[1];
        short8 xq = cvt8(x0, x1);
        #pragma unroll
        for (int dt = 0; dt < 4; ++dt) {
            int col = 16*dt + ln15;
            union { unsigned u[4]; short8 s; } rq;
            #pragma unroll
            for (int jj = 0; jj < 4; ++jj) {
                const float* qp = Wq + (quad*8 + 2*jj) * 64 + col;
                rq.u[jj] = pk_bf2(qp[0] * LOG2E, qp[64] * LOG2E);
            }
            floatx4 d = (floatx4){0.f, 0.f, 0.f, 0.f};
            d = MFMA16(rq.s, xq, d);   // col=q=ln15, row=d=16dt+quad*4+r
            int graw = 2*dt + (quad >> 1);
            *(ushort4_a*)(sQh + ln15*64 + ((graw ^ (ln15 & 7)) << 3)
                              + ((quad & 1) << 2)) = pack4(d);
        }
        union { uint4 u; short8 s; } t0, t1;    // same-wave readback (lgkmcnt)
        t0.u = sP[wave*128 + ln15*8 + (quad ^ (ln15 & 7))];
        t1.u = sP[wave*128 + ln15*8 + ((quad + 4) ^ (ln15 & 7))];
        bq0 = t0.s; bq1 = t1.s;
        #pragma unroll
        for (int c = 0; c < 4; ++c) o4[c] = (floatx4){0.f, 0.f, 0.f, 0.f};
        l_lane = 0.f;
    };

    auto flush = [&](int qtf) {        // atomicAdd partial (O, l) for q-tile qtf
        int q = qtf*64 + gw*16 + ln15;
        float* Ob = Oacc + (bT + q) * 64;
        #pragma unroll
        for (int c = 0; c < 4; ++c)
            #pragma unroll
            for (int r = 0; r < 4; ++r)
                atomicAdd(Ob + 16*c + quad*4 + r, o4[c][r]);
        float v = l_lane;
        v += __shfl_xor(v, 16);
        v += __shfl_xor(v, 32);
        if (quad == 0) atomicAdd(Lacc + bT + q, v);
    };

    regenQ(qt_c);

    // ---- x-slab prefetch for first tile (keys kt_c*64 + 16gw + ln15) ----
    float4 pX0, pX1;
    {
        const float* xp = x + (bT + kt_c*64 + 16*gw + ln15) * 32 + quad*8;
        pX0 = ((const float4_a*)xp)[0];
        pX1 = ((const float4_a*)xp)[1];
    }

    unsigned short* sKh = (unsigned short*)sK;
    unsigned short* sVh = (unsigned short*)sVt;
    int qrow = qt_c*64 + gw*16 + ln15;

    for (int it = 0; it < CPB; ++it) {
        __syncthreads();               // prev compute done -> LDS writable
        {   // ---- stage K and V^T via MFMA from prefetched x-slab ----
            short8 xf = cvt8(pX0, pX1);    // A-op (m=key) AND B-op (n=key)
            int key = 16*gw + ln15;
            #pragma unroll
            for (int c = 0; c < 4; ++c) {
                floatx4 dk = (floatx4){0.f, 0.f, 0.f, 0.f};
                dk = MFMA16(wk_f[c], xf, dk);  // col=key, row=d=16c+quad*4+r
                int g1 = 2*c + (quad >> 1);
                *(ushort4_a*)(sKh + key*64 + ((g1 ^ (key & 7)) << 3)
                                  + ((quad & 1) << 2)) = pack4(dk);
                floatx4 dv = (floatx4){0.f, 0.f, 0.f, 0.f};
                dv = MFMA16(xf, wv_f[c], dv);  // col=d=16c+ln15, row=key
                int dcol = 16*c + ln15;
                int g2 = 2*gw + (quad >> 1);
                *(ushort4_a*)(sVh + dcol*64 + ((g2 ^ (dcol & 7)) << 3)
                                  + ((quad & 1) << 2)) = pack4(dv);
            }
        }
        // next tile coords (block-uniform)
        int nq = qt_c, nk = kt_c + 1;
        bool newq = (nk > qt_c);
        if (newq) { nq = qt_c - 1; nk = 0; }
        if (it < CPB - 1) {            // prefetch next x-slab during compute
            const float* xp = x + (bT + nk*64 + 16*gw + ln15) * 32 + quad*8;
            pX0 = ((const float4_a*)xp)[0];
            pX1 = ((const float4_a*)xp)[1];
        }
        __syncthreads();               // tiles staged
        int k0 = kt_c * 64;

        // ---- S^T = K . Q^T : A = K rows (m=key), B = Q ----
        floatx4 s4[4];
        #pragma unroll
        for (int t = 0; t < 4; ++t) {
            int kr = 16*t + ln15;
            union { uint4 u; short8 s; } a0, a1;
            a0.u = sK[kr*8 + (quad ^ (ln15 & 7))];
            a1.u = sK[kr*8 + ((quad + 4) ^ (ln15 & 7))];
            floatx4 c = (floatx4){0.f, 0.f, 0.f, 0.f};
            c = MFMA16(a0.s, bq0, c);
            c = MFMA16(a1.s, bq1, c);
            s4[t] = c;
        }

        // ---- p = exp2(s), causal mask only on diagonal tile, P^T -> LDS ----
        unsigned long long* sP64 = (unsigned long long*)sP;
        const int pb = wave*256 + ln15*16;
        const int xk = ln15 & 14;
        if (kt_c == qt_c) {            // block-uniform branch
            #pragma unroll
            for (int t = 0; t < 4; ++t) {
                int keyb = k0 + 16*t + quad*4;
                float p[4];
                #pragma unroll
                for (int r = 0; r < 4; ++r) {
                    p[r] = (keyb + r <= qrow) ? __builtin_amdgcn_exp2f(s4[t][r]) : 0.f;
                    l_lane += p[r];
                }
                unsigned long long pk =
                    ((unsigned long long)pk_bf2(p[2], p[3]) << 32) | pk_bf2(p[0], p[1]);
                sP64[pb + ((4*t + quad) ^ xk)] = pk;
            }
        } else {
            #pragma unroll
            for (int t = 0; t < 4; ++t) {
                float p[4];
                #pragma unroll
                for (int r = 0; r < 4; ++r) {
                    p[r] = __builtin_amdgcn_exp2f(s4[t][r]);
                    l_lane += p[r];
                }
                unsigned long long pk =
                    ((unsigned long long)pk_bf2(p[2], p[3]) << 32) | pk_bf2(p[0], p[1]);
                sP64[pb + ((4*t + quad) ^ xk)] = pk;
            }
        }

        // ---- O^T += V^T . P^T : A = V^T rows (m=d), B = P^T ----
        int h = (ln15 >> 1) & 7;
        union { uint4 u; short8 s; } p0, p1;
        p0.u = sP[wave*128 + ln15*8 + (quad ^ h)];
        p1.u = sP[wave*128 + ln15*8 + ((quad + 4) ^ h)];
        #pragma unroll
        for (int c = 0; c < 4; ++c) {
            int dr = 16*c + ln15;
            union { uint4 u; short8 s; } v0, v1;
            v0.u = sVt[dr*8 + (quad ^ (dr & 7))];
            v1.u = sVt[dr*8 + ((quad + 4) ^ (dr & 7))];
            o4[c] = MFMA16(v0.s, p0.s, o4[c]);
            o4[c] = MFMA16(v1.s, p1.s, o4[c]);
        }

        // ---- advance: flush partials at qt boundary / block end ----
        if (it == CPB - 1) {
            flush(qt_c);
        } else if (newq) {
            flush(qt_c);
            regenQ(nq);                // per-wave, no barrier needed
            qrow = nq*64 + gw*16 + ln15;
        }
        qt_c = nq; kt_c = nk;
    }
}

// ---------------------------------------------------------------------------
__global__ __launch_bounds__(256) void norm_kernel(
    const float4* __restrict__ Oacc, const float* __restrict__ Lacc,
    float4* __restrict__ out)
{
    int i = blockIdx.x * 256 + threadIdx.x;   // 524288 float4 units
    float inv = 1.f / Lacc[i >> 4];
    float4 o = Oacc[i];
    out[i] = make_float4(o.x * inv, o.y * inv, o.z * inv, o.w * inv);
}

// ---------------------------------------------------------------------------
extern "C" void kernel_launch(void* const* d_in, const int* in_sizes, int n_in,
                              void* d_out, int out_size, void* d_ws, size_t ws_size,
                              hipStream_t stream)
{
    const float* x  = (const float*)d_in[0];
    const float* Wk = (const float*)d_in[1];   // setup_inputs order: x, Wk, Wq, Wv
    const float* Wq = (const float*)d_in[2];
    const float* Wv = (const float*)d_in[3];
    float* out = (float*)d_out;

    // workspace: Oacc [B*T*64 f32] (8 MB) | Lacc [B*T f32] (128 KB), contiguous
    float* Oacc = (float*)d_ws;
    float* Lacc = Oacc + (size_t)Bc * Tt * Dd;

    // zero Oacc+Lacc: (2097152 + 32768) f32 = 532480 float4 = 1040 * 512
    zero_kernel<<<1040, 512, 0, stream>>>((float4*)d_ws);
    attn_accum<<<Bc * BPB, 256, 0, stream>>>(x, Wk, Wq, Wv, Oacc, Lacc);
    norm_kernel<<<2048, 256, 0, stream>>>((const float4*)Oacc, Lacc, (float4*)out);
}

// Round 8
// 102.866 us; speedup vs baseline: 2.4752x; 2.4752x over previous
//
#include <hip/hip_runtime.h>
#include <hip/hip_bf16.h>

// B=8, T=4096, C=32, D=64. Causal, no 1/sqrt(D) scaling.
constexpr int Bc = 8;
constexpr int Tt = 4096;
constexpr int Dd = 64;

typedef __attribute__((ext_vector_type(8))) short short8;   // 8 bf16 = 4 VGPRs
typedef __attribute__((ext_vector_type(4))) float floatx4;  // MFMA C/D frag
typedef uint4   __attribute__((may_alias)) uint4_a;
typedef short8  __attribute__((may_alias)) short8_a;
typedef ushort4 __attribute__((may_alias)) ushort4_a;
typedef float4  __attribute__((may_alias)) float4_a;

#define MFMA16(A, B, C) __builtin_amdgcn_mfma_f32_16x16x32_bf16(A, B, C, 0, 0, 0)
constexpr float LOG2E = 1.4426950408889634f;

// ---- fast fp32 -> bf16: round-half-up (u + 0x8000), pack 2 via v_perm ----
__device__ __forceinline__ unsigned rnd16(float x) {
    unsigned u; __builtin_memcpy(&u, &x, 4); return u + 0x8000u;
}
__device__ __forceinline__ unsigned pk_bf2(float lo, float hi) {
    return __builtin_amdgcn_perm(rnd16(hi), rnd16(lo), 0x07060302);
}
__device__ __forceinline__ ushort4 pack4(floatx4 d) {
    union { unsigned u[2]; ushort4 v; } r;
    r.u[0] = pk_bf2(d[0], d[1]);
    r.u[1] = pk_bf2(d[2], d[3]);
    return r.v;
}
__device__ __forceinline__ short8 cvt8(float4 a, float4 b) {
    union { unsigned u[4]; short8 s; } r;
    r.u[0] = pk_bf2(a.x, a.y);
    r.u[1] = pk_bf2(a.z, a.w);
    r.u[2] = pk_bf2(b.x, b.y);
    r.u[3] = pk_bf2(b.z, b.w);
    return r.s;
}

// ---------------------------------------------------------------------------
// Fused flash attention, 1024-thread blocks = 16 waves = 4 split-K groups of
// 4 waves. Block handles the balanced qt-pair (63-pr, pr) sequentially:
// ceil((qtA+1)/4) + ceil((qtB+1)/4) == 17 k-tile iterations for EVERY block
// -> uniform duration, 16 waves/CU, 1 block/CU (grid=256, LDS=96KB).
// Group g takes k-tiles 4i+g; partial (O, l) merged ADDITIVELY in LDS at each
// phase end (no-max softmax => partials combine by pure addition; no global
// atomics - R7 lesson). K/V^T regenerated per-tile in LDS via MFMA from x and
// register W-frags; Q regenerated per phase (one MFMA per wave) through LDS.
// ---------------------------------------------------------------------------
__global__ __launch_bounds__(1024) void attn_kernel(
    const float* __restrict__ x,
    const float* __restrict__ Wk, const float* __restrict__ Wq,
    const float* __restrict__ Wv,
    float* __restrict__ out)
{
    __shared__ uint4 sStage[4096];  // 64 KB: group g: sK=g*1024(+512 uint4=sVt)
    __shared__ uint4 sP[2048];      // 32 KB: wave w slot w*128; sQ=[0..511] transient

    int b  = blockIdx.x & 7;
    int pr = blockIdx.x >> 3;            // 0..31
    int tid  = threadIdx.x;
    int wave = tid >> 6, lane = tid & 63;
    int group = wave >> 2, gw = wave & 3;
    int ln15 = lane & 15, quad = lane >> 4;
    size_t bT = (size_t)b * Tt;

    // ---- loop/phase-invariant W fragments (lane -> (d=16c+ln15, k=quad*8+j)) ----
    short8 wk_f[4], wv_f[4];
    #pragma unroll
    for (int c = 0; c < 4; ++c) {
        int col = 16*c + ln15;
        union { unsigned u[4]; short8 s; } rk, rv;
        #pragma unroll
        for (int jj = 0; jj < 4; ++jj) {
            const float* k0 = Wk + (quad*8 + 2*jj) * 64 + col;
            const float* v0 = Wv + (quad*8 + 2*jj) * 64 + col;
            rk.u[jj] = pk_bf2(k0[0], k0[64]);
            rv.u[jj] = pk_bf2(v0[0], v0[64]);
        }
        wk_f[c] = rk.s; wv_f[c] = rv.s;
    }
    // Wq A-frag for this wave's Q-regen tile (phase-invariant): d col = 16dt+ln15
    short8 wq_f;
    {
        int dt = wave >> 2, colD = 16*dt + ln15;
        union { unsigned u[4]; short8 s; } rq;
        #pragma unroll
        for (int jj = 0; jj < 4; ++jj) {
            const float* qp = Wq + (quad*8 + 2*jj) * 64 + colD;
            rq.u[jj] = pk_bf2(qp[0] * LOG2E, qp[64] * LOG2E);
        }
        wq_f = rq.s;
    }

    const int stK = group * 1024;        // uint4 idx of group's sK tile
    const int stV = group * 1024 + 512;  // uint4 idx of group's sVt tile
    unsigned short* sSh = (unsigned short*)sStage;
    const int stK_h = stK * 8, stV_h = stV * 8;

    #pragma unroll
    for (int phase = 0; phase < 2; ++phase) {
        const int qtP = (phase == 0) ? (63 - pr) : pr;
        const int q0 = qtP * 64;
        const int qrow = q0 + gw*16 + ln15;

        // ---- Q regen: wave w computes q-sub (w&3) x d-tile (w>>2), 1 MFMA ----
        {
            int qs = wave & 3, dt = wave >> 2;
            const float* xp = x + (bT + q0 + qs*16 + ln15)*32 + quad*8;
            float4 x0 = ((const float4_a*)xp)[0];
            float4 x1 = ((const float4_a*)xp)[1];
            short8 xq = cvt8(x0, x1);
            floatx4 d = (floatx4){0.f, 0.f, 0.f, 0.f};
            d = MFMA16(wq_f, xq, d);   // col=q local=ln15, row=d=16dt+quad*4+r
            int ql = qs*16 + ln15;
            int graw = 2*dt + (quad >> 1);
            unsigned short* sQh = (unsigned short*)sP;
            *(ushort4_a*)(sQh + ql*64 + ((graw ^ (ql & 7)) << 3)
                              + ((quad & 1) << 2)) = pack4(d);
        }
        __syncthreads();
        short8 bq0, bq1;               // Q B-frags (n=q=ln15, k=quad*8+j)
        {
            int ql = gw*16 + ln15;
            union { uint4 u; short8 s; } t0, t1;
            t0.u = sP[ql*8 + (quad ^ (ql & 7))];
            t1.u = sP[ql*8 + ((quad + 4) ^ (ql & 7))];
            bq0 = t0.s; bq1 = t1.s;
        }
        floatx4 o4[4];
        #pragma unroll
        for (int c = 0; c < 4; ++c) o4[c] = (floatx4){0.f, 0.f, 0.f, 0.f};
        float l_lane = 0.f;

        const int nIter = (qtP + 4) >> 2;   // ceil((qtP+1)/4)
        float4 pX0, pX1;
        if (group <= qtP) {            // prologue x-slab (keys of k-tile=group)
            const float* xp = x + (bT + group*64 + 16*gw + ln15)*32 + quad*8;
            pX0 = ((const float4_a*)xp)[0];
            pX1 = ((const float4_a*)xp)[1];
        }

        for (int it = 0; it < nIter; ++it) {
            int kt = 4*it + group;
            bool active = (kt <= qtP);
            __syncthreads();           // prev compute / bq reads / merge done
            if (active) {              // stage K and V^T via MFMA from x-slab
                short8 xf = cvt8(pX0, pX1);   // A-op (m=key) AND B-op (n=key)
                int key = 16*gw + ln15;
                #pragma unroll
                for (int c = 0; c < 4; ++c) {
                    floatx4 dk = (floatx4){0.f, 0.f, 0.f, 0.f};
                    dk = MFMA16(wk_f[c], xf, dk);  // col=key, row=d=16c+quad*4+r
                    int g1 = 2*c + (quad >> 1);
                    *(ushort4_a*)(sSh + stK_h + key*64 + ((g1 ^ (key & 7)) << 3)
                                      + ((quad & 1) << 2)) = pack4(dk);
                    floatx4 dv = (floatx4){0.f, 0.f, 0.f, 0.f};
                    dv = MFMA16(xf, wv_f[c], dv);  // col=d=16c+ln15, row=key
                    int dcol = 16*c + ln15;
                    int g2 = 2*gw + (quad >> 1);
                    *(ushort4_a*)(sSh + stV_h + dcol*64 + ((g2 ^ (dcol & 7)) << 3)
                                      + ((quad & 1) << 2)) = pack4(dv);
                }
            }
            int ktn = kt + 4;          // prefetch next x-slab during compute
            if (ktn <= qtP) {
                const float* xp = x + (bT + ktn*64 + 16*gw + ln15)*32 + quad*8;
                pX0 = ((const float4_a*)xp)[0];
                pX1 = ((const float4_a*)xp)[1];
            }
            __syncthreads();           // tiles staged
            if (!active) continue;
            int k0 = kt * 64;

            // ---- S^T = K . Q^T : A = K rows (m=key), B = Q ----
            floatx4 s4[4];
            #pragma unroll
            for (int t = 0; t < 4; ++t) {
                int kr = 16*t + ln15;
                union { uint4 u; short8 s; } a0, a1;
                a0.u = sStage[stK + kr*8 + (quad ^ (ln15 & 7))];
                a1.u = sStage[stK + kr*8 + ((quad + 4) ^ (ln15 & 7))];
                floatx4 c = (floatx4){0.f, 0.f, 0.f, 0.f};
                c = MFMA16(a0.s, bq0, c);
                c = MFMA16(a1.s, bq1, c);
                s4[t] = c;
            }

            // ---- p = exp2(s), mask only on diagonal tile, P^T -> LDS ----
            unsigned long long* sP64 = (unsigned long long*)sP;
            const int pb = wave*256 + ln15*16;
            const int xk = ln15 & 14;
            if (kt == qtP) {           // wave-uniform branch
                #pragma unroll
                for (int t = 0; t < 4; ++t) {
                    int keyb = k0 + 16*t + quad*4;
                    float p[4];
                    #pragma unroll
                    for (int r = 0; r < 4; ++r) {
                        p[r] = (keyb + r <= qrow) ? __builtin_amdgcn_exp2f(s4[t][r]) : 0.f;
                        l_lane += p[r];
                    }
                    unsigned long long pk =
                        ((unsigned long long)pk_bf2(p[2], p[3]) << 32) | pk_bf2(p[0], p[1]);
                    sP64[pb + ((4*t + quad) ^ xk)] = pk;
                }
            } else {
                #pragma unroll
                for (int t = 0; t < 4; ++t) {
                    float p[4];
                    #pragma unroll
                    for (int r = 0; r < 4; ++r) {
                        p[r] = __builtin_amdgcn_exp2f(s4[t][r]);
                        l_lane += p[r];
                    }
                    unsigned long long pk =
                        ((unsigned long long)pk_bf2(p[2], p[3]) << 32) | pk_bf2(p[0], p[1]);
                    sP64[pb + ((4*t + quad) ^ xk)] = pk;
                }
            }

            // ---- O^T += V^T . P^T : A = V^T rows (m=d), B = P^T ----
            int h = (ln15 >> 1) & 7;
            union { uint4 u; short8 s; } p0, p1;
            p0.u = sP[wave*128 + ln15*8 + (quad ^ h)];
            p1.u = sP[wave*128 + ln15*8 + ((quad + 4) ^ h)];
            #pragma unroll
            for (int c = 0; c < 4; ++c) {
                int dr = 16*c + ln15;
                union { uint4 u; short8 s; } v0, v1;
                v0.u = sStage[stV + dr*8 + (quad ^ (dr & 7))];
                v1.u = sStage[stV + dr*8 + ((quad + 4) ^ (dr & 7))];
                o4[c] = MFMA16(v0.s, p0.s, o4[c]);
                o4[c] = MFMA16(v1.s, p1.s, o4[c]);
            }
        }

        // ---- merge 4 groups' partials additively in LDS; group 0 stores ----
        __syncthreads();               // all compute done; staging areas free
        int li = gw*64 + lane;         // 0..255 within group
        ((float*)sP)[wave*64 + lane] = l_lane;      // l partial (group*256+li)
        if (group != 0) {
            float4* st = (float4*)(sStage + group*1024);  // group's 16 KB area
            #pragma unroll
            for (int c = 0; c < 4; ++c)
                st[c*256 + li] = make_float4(o4[c][0], o4[c][1], o4[c][2], o4[c][3]);
        }
        __syncthreads();
        if (group == 0) {
            float l = l_lane + ((float*)sP)[256 + li]
                    + ((float*)sP)[512 + li] + ((float*)sP)[768 + li];
            l += __shfl_xor(l, 16);    // quads hold disjoint key subsets
            l += __shfl_xor(l, 32);
            float inv = 1.f / l;
            #pragma unroll
            for (int c = 0; c < 4; ++c) {
                float ax = o4[c][0], ay = o4[c][1], az = o4[c][2], aw = o4[c][3];
                #pragma unroll
                for (int g = 1; g < 4; ++g) {
                    float4 p = ((float4*)(sStage + g*1024))[c*256 + li];
                    ax += p.x; ay += p.y; az += p.z; aw += p.w;
                }
                // O^T C-layout: q = ln15 (col), d = 16c + quad*4 + r (row)
                *(float4_a*)(out + (bT + q0 + gw*16 + ln15) * Dd + 16*c + quad*4)
                    = make_float4(ax*inv, ay*inv, az*inv, aw*inv);
            }
        }
        __syncthreads();               // merge reads done before next phase's
                                       // Q-regen / staging overwrite LDS
    }
}

// ---------------------------------------------------------------------------
extern "C" void kernel_launch(void* const* d_in, const int* in_sizes, int n_in,
                              void* d_out, int out_size, void* d_ws, size_t ws_size,
                              hipStream_t stream)
{
    const float* x  = (const float*)d_in[0];
    const float* Wk = (const float*)d_in[1];   // setup_inputs order: x, Wk, Wq, Wv
    const float* Wq = (const float*)d_in[2];
    const float* Wv = (const float*)d_in[3];
    float* out = (float*)d_out;

    // 256 blocks (one per CU), 1024 threads, 96 KB LDS, uniform 17 iterations
    attn_kernel<<<Bc * 32, 1024, 0, stream>>>(x, Wk, Wq, Wv, out);
}